// Round 20
// baseline (255.859 us; speedup 1.0000x reference)
//
#include <hip/hip_runtime.h>
#include <math.h>

// Capsule dynamic routing v21 — barrier-free routing (1 wave per batch).
// R19: killing LDS conflicts moved nothing -> they were overlapped. The real
// serializer: routing's 3 block-wide barriers convoy all 8 waves, so the two
// resident blocks' phases SUM (54.7 ~= 29us VMEM + 25us routing) instead of
// pipelining. v21: after the single park barrier, wave 0 routes batch 0 and
// wave 1 routes batch 1 ENTIRELY in-wave (rows r=gg+jj*16, jj=0..71; shuffle
// reductions only, ZERO barriers); waves 2-7 retire, freeing SIMD slots.
// Steady state: block N's 8-wave priors VMEM overlaps block N-1's 2-wave
// routing -> per-CU period ~= priors time ~= 29us total.
// Park read is lane-linear (slot=((jj&7)<<6)|lane): conflict-free.
// LDS = park only (73.7KB) -> 2 blocks/CU kept.
//
// x: [B=256, R=1152, I=8] f32 ; W: [C=10, R=1152, I=8, O=16] f32
// out: [B=256, C=10, O=16] f32
//
// One block per (c, b-pair). T=512, 8 waves.
// Priors: g=t>>2 (128 groups), q=t&3; rows r=g+j*128, j=0..8; both batches
// (G=2 fan-out: one W float4 feeds 8 FMAs). Park fp16 [j][bsel][t].

#define C_CAPS 10
#define B_SZ   256
#define R_SZ   1152
#define I_SZ   8
#define O_SZ   16
#define T_THREADS 512
#define RPT_P 9
#define RPT_R 72     // rows per routing lane-group: 1152/16

static __device__ __forceinline__ unsigned int pack2h(float a, float b) {
    const _Float16 ha = (_Float16)a, hb = (_Float16)b;
    const unsigned short ua = __builtin_bit_cast(unsigned short, ha);
    const unsigned short ub = __builtin_bit_cast(unsigned short, hb);
    return (unsigned int)ua | ((unsigned int)ub << 16);
}
static __device__ __forceinline__ float h2f_lo(unsigned int u) {
    const _Float16 h = __builtin_bit_cast(_Float16, (unsigned short)(u & 0xffffu));
    return (float)h;
}
static __device__ __forceinline__ float h2f_hi(unsigned int u) {
    const _Float16 h = __builtin_bit_cast(_Float16, (unsigned short)(u >> 16));
    return (float)h;
}

__global__ __launch_bounds__(T_THREADS, 1) void capsule_kernel(
    const float* __restrict__ x,
    const float* __restrict__ w,
    float* __restrict__ out)
{
    const int c  = blockIdx.x >> 7;        // / (B/2)
    const int bb = blockIdx.x & 127;
    const int b0 = bb * 2;
    const int t = (int)threadIdx.x;
    const int lane = t & 63;
    const int wid = t >> 6;

    __shared__ uint2 Plds[RPT_P][2][T_THREADS];   // [j][bsel][park-thread] 73728B

    // ================= priors phase: G=2 fan-out (v19/v20 proven) =================
    {
        const int g = t >> 2;              // 0..127
        const int q = t & 3;
        const float* xp0 = x + ((size_t)b0 * R_SZ + g) * I_SZ;
        const float* xp1 = xp0 + (size_t)R_SZ * I_SZ;
        const float* wr  = w + ((size_t)c * R_SZ + g) * (I_SZ * O_SZ) + q * 4;
        const size_t xstep = (size_t)128 * I_SZ;
        const size_t wstep = (size_t)128 * I_SZ * O_SZ;

        #pragma unroll
        for (int j = 0; j < RPT_P; ++j) {
            const float4 x0a = *(const float4*)(xp0 + j * xstep);
            const float4 x0b = *(const float4*)(xp0 + j * xstep + 4);
            const float4 x1a = *(const float4*)(xp1 + j * xstep);
            const float4 x1b = *(const float4*)(xp1 + j * xstep + 4);
            const float xi0[I_SZ] = {x0a.x, x0a.y, x0a.z, x0a.w,
                                     x0b.x, x0b.y, x0b.z, x0b.w};
            const float xi1[I_SZ] = {x1a.x, x1a.y, x1a.z, x1a.w,
                                     x1b.x, x1b.y, x1b.z, x1b.w};
            const float* wj = wr + j * wstep;
            float a00=0.f, a01=0.f, a02=0.f, a03=0.f;
            float a10=0.f, a11=0.f, a12=0.f, a13=0.f;
            #pragma unroll
            for (int i = 0; i < I_SZ; ++i) {
                const float4 wv = *(const float4*)(wj + i * O_SZ);  // feeds 8 FMA
                a00 = fmaf(xi0[i], wv.x, a00);
                a01 = fmaf(xi0[i], wv.y, a01);
                a02 = fmaf(xi0[i], wv.z, a02);
                a03 = fmaf(xi0[i], wv.w, a03);
                a10 = fmaf(xi1[i], wv.x, a10);
                a11 = fmaf(xi1[i], wv.y, a11);
                a12 = fmaf(xi1[i], wv.z, a12);
                a13 = fmaf(xi1[i], wv.w, a13);
            }
            uint2 p0, p1;
            p0.x = pack2h(a00, a01); p0.y = pack2h(a02, a03);
            p1.x = pack2h(a10, a11); p1.y = pack2h(a12, a13);
            Plds[j][0][t] = p0;                 // thread-linear writes: free
            Plds[j][1][t] = p1;
        }
    }
    __syncthreads();     // the ONLY barrier in the kernel

    // ================= routing phase: 1 wave per batch, barrier-free ==========
    if (wid >= 2) return;                  // waves 2-7 retire, free the SIMDs
    const int bsel = wid;                  // wave 0 -> batch b0, wave 1 -> b0+1
    const int q2 = lane & 3;

    float logit[RPT_R];
    #pragma unroll
    for (int jj = 0; jj < RPT_R; ++jj) logit[jj] = 0.0f;

    float vq[4];

    for (int it = 0; it < 3; ++it) {
        // ---- fused exp + weighted-sum partials; lane-linear LDS reads ----
        float sa0 = 0.f, sa1 = 0.f, sa2 = 0.f, sa3 = 0.f, zp = 0.f;
        #pragma unroll
        for (int jj = 0; jj < RPT_R; ++jj) {
            // row r = (lane>>2) + jj*16 -> park slot j=jj>>3, idx=((jj&7)<<6)|lane
            const uint2 pp = Plds[jj >> 3][bsel][((jj & 7) << 6) | lane];
            const float e = __expf(logit[jj]);   // it==0: exp(0)=1 exactly
            zp += e;
            sa0 = fmaf(e, h2f_lo(pp.x), sa0);
            sa1 = fmaf(e, h2f_hi(pp.x), sa1);
            sa2 = fmaf(e, h2f_lo(pp.y), sa2);
            sa3 = fmaf(e, h2f_hi(pp.y), sa3);
        }
        // reduce over the 16 lane-groups (row axis): masks 4..32, in-wave only
        #pragma unroll
        for (int m = 4; m <= 32; m <<= 1) {
            sa0 += __shfl_xor(sa0, m, 64);
            sa1 += __shfl_xor(sa1, m, 64);
            sa2 += __shfl_xor(sa2, m, 64);
            sa3 += __shfl_xor(sa3, m, 64);
            zp  += __shfl_xor(zp,  m, 64);
        }
        // every lane now holds s[q2-quad] and Z (butterfly = all-reduce)

        // ---- normalize + squash (normalize BEFORE squaring: overflow-safe) ----
        const float invZ = 1.0f / zp;
        const float u0 = sa0 * invZ, u1 = sa1 * invZ,
                    u2 = sa2 * invZ, u3 = sa3 * invZ;
        float nq = u0*u0 + u1*u1 + u2*u2 + u3*u3;
        nq += __shfl_xor(nq, 1, 64);           // sum over the 4 q-quads
        nq += __shfl_xor(nq, 2, 64);
        const float scale = nq / ((1.0f + nq) * sqrtf(nq));
        vq[0] = scale * u0; vq[1] = scale * u1;
        vq[2] = scale * u2; vq[3] = scale * u3;

        // ---- logit update (iters 0,1): logit[r] += P[r]·v ----
        if (it < 2) {
            #pragma unroll
            for (int jj = 0; jj < RPT_R; ++jj) {
                const uint2 pp = Plds[jj >> 3][bsel][((jj & 7) << 6) | lane];
                float d = h2f_lo(pp.x)*vq[0] + h2f_hi(pp.x)*vq[1]
                        + h2f_lo(pp.y)*vq[2] + h2f_hi(pp.y)*vq[3];
                d += __shfl_xor(d, 1, 64);
                d += __shfl_xor(d, 2, 64);
                logit[jj] += d;
            }
        }
    }

    // ---- write out[b0+bsel, c, :]: lanes 0..3 hold quads 0..3 ----
    if (lane < 4) {
        float* op = out + ((size_t)(b0 + bsel) * C_CAPS + c) * O_SZ + q2 * 4;
        *(float4*)op = make_float4(vq[0], vq[1], vq[2], vq[3]);
    }
}

extern "C" void kernel_launch(void* const* d_in, const int* in_sizes, int n_in,
                              void* d_out, int out_size, void* d_ws, size_t ws_size,
                              hipStream_t stream) {
    const float* x = (const float*)d_in[0];
    const float* w = (const float*)d_in[1];
    float* out = (float*)d_out;
    dim3 grid(C_CAPS * (B_SZ / 2));
    dim3 block(T_THREADS);
    hipLaunchKernelGGL(capsule_kernel, grid, block, 0, stream, x, w, out);
}

// Round 21
// 52.610 us; speedup vs baseline: 4.8634x; 4.8634x over previous
//
#include <hip/hip_runtime.h>
#include <math.h>

// Capsule dynamic routing v22 — v20 + fused routing sweeps.
// R20: v21 (1-wave routing, logit[72]) spilled catastrophically -> revert.
// v20 analysis: phases of the 2 resident blocks run in LOCKSTEP (launched
// together) so priors-VMEM and routing-VALU sum (29+25us). Can't stagger
// dispatch from source -> shrink routing instead:
//   - v20 swept P from LDS 5x (3 s-sweeps + 2 logit-sweeps). v22 fuses
//     logit-update(it) into s-accum(it+1): one sweep does
//     d=P·v; logit+=d; e=exp(logit); s+=e*P.  -> 3 sweeps total.
//   - pass 0: all logits are 0 -> e=1, Z=1152 EXACTLY: no exp, no Z-reduce.
// Geometry, park phase, lane-linear reads, parity-buffered single-barrier
// reduction: v20 verbatim (proven 54.7us, VGPR 56, 0 conflicts).
// Parity proof: pass2 writes red_s[0] only after pass1's barrier; pass0's
// red_s[0] readers all finished before that barrier. No race.
//
// x: [B=256, R=1152, I=8] f32 ; W: [C=10, R=1152, I=8, O=16] f32
// out: [B=256, C=10, O=16] f32
//
// One block per (c, b-pair). T=512, 8 waves; LDS ~75KB -> 2 blocks/CU.
// Priors: g=t>>2 (128 groups), q=t&3; rows r=g+j*128, j=0..8; both batches.
// Routing: q2=t&3, g2=(t>>2)&63, bsel=t>>8; rows r=g2+jj*64, jj=0..17.

#define C_CAPS 10
#define B_SZ   256
#define R_SZ   1152
#define I_SZ   8
#define O_SZ   16
#define T_THREADS 512
#define RPT_P 9
#define RPT_R 18
#define NW 8

static __device__ __forceinline__ unsigned int pack2h(float a, float b) {
    const _Float16 ha = (_Float16)a, hb = (_Float16)b;
    const unsigned short ua = __builtin_bit_cast(unsigned short, ha);
    const unsigned short ub = __builtin_bit_cast(unsigned short, hb);
    return (unsigned int)ua | ((unsigned int)ub << 16);
}
static __device__ __forceinline__ float h2f_lo(unsigned int u) {
    const _Float16 h = __builtin_bit_cast(_Float16, (unsigned short)(u & 0xffffu));
    return (float)h;
}
static __device__ __forceinline__ float h2f_hi(unsigned int u) {
    const _Float16 h = __builtin_bit_cast(_Float16, (unsigned short)(u >> 16));
    return (float)h;
}

__global__ __launch_bounds__(T_THREADS, 1) void capsule_kernel(
    const float* __restrict__ x,
    const float* __restrict__ w,
    float* __restrict__ out)
{
    const int c  = blockIdx.x >> 7;        // / (B/2)
    const int bb = blockIdx.x & 127;
    const int b0 = bb * 2;
    const int t = (int)threadIdx.x;
    const int lane = t & 63;
    const int wid = t >> 6;

    __shared__ uint2  Plds[RPT_P][2][T_THREADS];   // [j][bsel][park-thread] 73728B
    __shared__ float4 red_s[2][NW][4];             // parity, wave, q2
    __shared__ float  red_z[2][NW];

    // ================= priors phase: G=2 fan-out (v19/v20 proven) =================
    {
        const int g = t >> 2;              // 0..127
        const int q = t & 3;
        const float* xp0 = x + ((size_t)b0 * R_SZ + g) * I_SZ;
        const float* xp1 = xp0 + (size_t)R_SZ * I_SZ;
        const float* wr  = w + ((size_t)c * R_SZ + g) * (I_SZ * O_SZ) + q * 4;
        const size_t xstep = (size_t)128 * I_SZ;
        const size_t wstep = (size_t)128 * I_SZ * O_SZ;

        #pragma unroll
        for (int j = 0; j < RPT_P; ++j) {
            const float4 x0a = *(const float4*)(xp0 + j * xstep);
            const float4 x0b = *(const float4*)(xp0 + j * xstep + 4);
            const float4 x1a = *(const float4*)(xp1 + j * xstep);
            const float4 x1b = *(const float4*)(xp1 + j * xstep + 4);
            const float xi0[I_SZ] = {x0a.x, x0a.y, x0a.z, x0a.w,
                                     x0b.x, x0b.y, x0b.z, x0b.w};
            const float xi1[I_SZ] = {x1a.x, x1a.y, x1a.z, x1a.w,
                                     x1b.x, x1b.y, x1b.z, x1b.w};
            const float* wj = wr + j * wstep;
            float a00=0.f, a01=0.f, a02=0.f, a03=0.f;
            float a10=0.f, a11=0.f, a12=0.f, a13=0.f;
            #pragma unroll
            for (int i = 0; i < I_SZ; ++i) {
                const float4 wv = *(const float4*)(wj + i * O_SZ);  // feeds 8 FMA
                a00 = fmaf(xi0[i], wv.x, a00);
                a01 = fmaf(xi0[i], wv.y, a01);
                a02 = fmaf(xi0[i], wv.z, a02);
                a03 = fmaf(xi0[i], wv.w, a03);
                a10 = fmaf(xi1[i], wv.x, a10);
                a11 = fmaf(xi1[i], wv.y, a11);
                a12 = fmaf(xi1[i], wv.z, a12);
                a13 = fmaf(xi1[i], wv.w, a13);
            }
            uint2 p0, p1;
            p0.x = pack2h(a00, a01); p0.y = pack2h(a02, a03);
            p1.x = pack2h(a10, a11); p1.y = pack2h(a12, a13);
            Plds[j][0][t] = p0;                 // thread-linear writes: free
            Plds[j][1][t] = p1;
        }
    }
    __syncthreads();     // routing reads other threads' parks

    // ================= routing phase: 3 fused sweeps =================
    const int q2   = t & 3;
    const int bsel = t >> 8;               // waves 0-3: bsel 0; waves 4-7: bsel 1
    const int p_lo = t & 255;              // park-thread low index

    float logit[RPT_R];
    #pragma unroll
    for (int jj = 0; jj < RPT_R; ++jj) logit[jj] = 0.0f;

    float vq[4];

    // -------- pass 0: logits all 0 -> e=1, Z=1152 exactly --------
    {
        float sa0 = 0.f, sa1 = 0.f, sa2 = 0.f, sa3 = 0.f;
        #pragma unroll
        for (int jj = 0; jj < RPT_R; ++jj) {
            const uint2 pp = Plds[jj >> 1][bsel][p_lo | ((jj & 1) << 8)];
            sa0 += h2f_lo(pp.x);
            sa1 += h2f_hi(pp.x);
            sa2 += h2f_lo(pp.y);
            sa3 += h2f_hi(pp.y);
        }
        #pragma unroll
        for (int m = 4; m <= 32; m <<= 1) {
            sa0 += __shfl_xor(sa0, m, 64);
            sa1 += __shfl_xor(sa1, m, 64);
            sa2 += __shfl_xor(sa2, m, 64);
            sa3 += __shfl_xor(sa3, m, 64);
        }
        if (lane < 4) red_s[0][wid][lane] = make_float4(sa0, sa1, sa2, sa3);
        __syncthreads();

        const int wbase = bsel << 2;
        float4 sf = red_s[0][wbase][q2];
        #pragma unroll
        for (int k = 1; k < 4; ++k) {
            const float4 rr = red_s[0][wbase + k][q2];
            sf.x += rr.x; sf.y += rr.y; sf.z += rr.z; sf.w += rr.w;
        }
        const float invZ = 1.0f / (float)R_SZ;       // Z = 1152 exactly
        const float u0 = sf.x * invZ, u1 = sf.y * invZ,
                    u2 = sf.z * invZ, u3 = sf.w * invZ;
        float nq = u0*u0 + u1*u1 + u2*u2 + u3*u3;
        nq += __shfl_xor(nq, 1, 64);
        nq += __shfl_xor(nq, 2, 64);
        const float scale = nq / ((1.0f + nq) * sqrtf(nq));
        vq[0] = scale * u0; vq[1] = scale * u1;
        vq[2] = scale * u2; vq[3] = scale * u3;
    }

    // -------- passes 1,2: fused logit-update + exp + s-accum --------
    #pragma unroll
    for (int p = 1; p < 3; ++p) {
        const int pb = p & 1;
        float sa0 = 0.f, sa1 = 0.f, sa2 = 0.f, sa3 = 0.f, zp = 0.f;
        #pragma unroll
        for (int jj = 0; jj < RPT_R; ++jj) {
            const uint2 pp = Plds[jj >> 1][bsel][p_lo | ((jj & 1) << 8)];
            const float P0 = h2f_lo(pp.x), P1 = h2f_hi(pp.x);
            const float P2 = h2f_lo(pp.y), P3 = h2f_hi(pp.y);
            float d = P0*vq[0] + P1*vq[1] + P2*vq[2] + P3*vq[3];
            d += __shfl_xor(d, 1, 64);             // sum the 4 o-quads
            d += __shfl_xor(d, 2, 64);
            logit[jj] += d;
            const float e = __expf(logit[jj]);     // |logit|<=~40: f32-safe
            zp += e;
            sa0 = fmaf(e, P0, sa0);
            sa1 = fmaf(e, P1, sa1);
            sa2 = fmaf(e, P2, sa2);
            sa3 = fmaf(e, P3, sa3);
        }
        #pragma unroll
        for (int m = 4; m <= 32; m <<= 1) {
            sa0 += __shfl_xor(sa0, m, 64);
            sa1 += __shfl_xor(sa1, m, 64);
            sa2 += __shfl_xor(sa2, m, 64);
            sa3 += __shfl_xor(sa3, m, 64);
            zp  += __shfl_xor(zp,  m, 64);
        }
        if (lane < 4) red_s[pb][wid][lane] = make_float4(sa0, sa1, sa2, sa3);
        if (lane == 0) red_z[pb][wid] = zp;
        __syncthreads();

        const int wbase = bsel << 2;
        float4 sf = red_s[pb][wbase][q2];
        float Z = red_z[pb][wbase];
        #pragma unroll
        for (int k = 1; k < 4; ++k) {
            const float4 rr = red_s[pb][wbase + k][q2];
            sf.x += rr.x; sf.y += rr.y; sf.z += rr.z; sf.w += rr.w;
            Z += red_z[pb][wbase + k];
        }
        const float invZ = 1.0f / Z;
        const float u0 = sf.x * invZ, u1 = sf.y * invZ,
                    u2 = sf.z * invZ, u3 = sf.w * invZ;
        float nq = u0*u0 + u1*u1 + u2*u2 + u3*u3;
        nq += __shfl_xor(nq, 1, 64);
        nq += __shfl_xor(nq, 2, 64);
        const float scale = nq / ((1.0f + nq) * sqrtf(nq));
        vq[0] = scale * u0; vq[1] = scale * u1;
        vq[2] = scale * u2; vq[3] = scale * u3;
    }

    // ---- write out[b0+bsel, c, :] — one thread per (bsel, q2) ----
    if ((t & 255) < 4) {                       // t = 0..3 (bsel 0), 256..259 (bsel 1)
        float* op = out + ((size_t)(b0 + bsel) * C_CAPS + c) * O_SZ + q2 * 4;
        *(float4*)op = make_float4(vq[0], vq[1], vq[2], vq[3]);
    }
}

extern "C" void kernel_launch(void* const* d_in, const int* in_sizes, int n_in,
                              void* d_out, int out_size, void* d_ws, size_t ws_size,
                              hipStream_t stream) {
    const float* x = (const float*)d_in[0];
    const float* w = (const float*)d_in[1];
    float* out = (float*)d_out;
    dim3 grid(C_CAPS * (B_SZ / 2));
    dim3 block(T_THREADS);
    hipLaunchKernelGGL(capsule_kernel, grid, block, 0, stream, x, w, out);
}